// Round 10
// baseline (297.264 us; speedup 1.0000x reference)
//
#include <hip/hip_runtime.h>

// B=32, T=2048, D=128, H=256. fp32 in/out. SINGLE dispatch.
// 2-phase, 2-barrier wave-specialized megakernel, grid (8,32), 1024 threads.
// Chunk = 256 t (finer T-chunking fails numerically), warmup = 128 t,
// subchunk = 32 t, 13 iterations (+1 epilogue).
// KEY CHANGE vs R9: __launch_bounds__(1024) with NO waves/EU arg. R9's
// (1024,4) over-constrained the allocator to 64 VGPR/wave -> wf/pfx/hv all
// spilled to scratch (FETCH 504 MB, 226 us). A 1024-thread block must be
// launchable -> compiler caps at 128 VGPR/wave, which this partition fits
// (S-waves ~115, G-waves ~100). Occupancy 4 waves/SIMD, no spill.
// Work partition (bit-exact vs R0 accumulation orders, absmax 0.015625):
//   GEMM2: 8 S-waves (w0-7) x 1 col-block (col 16w+fr), per-col ks/plane order
//   GEMM1: 8 G-waves (w8-15) x 2 col-blocks (col 32gG+16j+fr), k0/plane order
//   scan1 tid<256 / scan2 tid in [256,384) / stage tid in [384,512)
//   LN: 32 rows over 16 waves (2 rows/wave), per-row math identical
//
// LDS 123,392 B (<= 160 KiB; 1 block/CU):
//   h1T[256*36] f32 (36,864)  h2T[128*36] f32 (18,432)
//   s2buf[2][32*132] f32 (33,792)  spkbuf[32*264] fp16 (16,896)
//   xb[2][32*136] fp16 (17,408)

typedef _Float16 half8 __attribute__((ext_vector_type(8)));
typedef float f32x4 __attribute__((ext_vector_type(4)));

#define MFMA_F16(a, b, c) __builtin_amdgcn_mfma_f32_16x16x32_f16(a, b, c, 0, 0, 0)

__device__ __forceinline__ unsigned short h2u(_Float16 h) {
    union { _Float16 h; unsigned short u; } x; x.h = h; return x.u;
}

__device__ __forceinline__ void split8(float4 f0, float4 f1, half8& a, half8& b) {
    float fs[8] = {f0.x, f0.y, f0.z, f0.w, f1.x, f1.y, f1.z, f1.w};
    half8 ha, hb;
#pragma unroll
    for (int q = 0; q < 8; ++q) {
        ha[q] = (_Float16)fs[q];
        hb[q] = (_Float16)(fs[q] - (float)ha[q]);
    }
    a = ha; b = hb;
}

__global__ __launch_bounds__(1024) void mega_kernel(
    const float* __restrict__ X,
    const float* __restrict__ W1, const float* __restrict__ W2,
    const float* __restrict__ b1, const float* __restrict__ b2,
    const float* __restrict__ lnw, const float* __restrict__ lnb,
    float* __restrict__ out)
{
    __shared__ __align__(16) float h1T[256 * 36];                   // 36,864 B
    __shared__ __align__(16) float h2T[128 * 36];                   // 18,432 B
    __shared__ __align__(16) float s2buf[2][32 * 132];              // 33,792 B
    __shared__ __align__(16) unsigned short spkbuf[32 * 264];       // 16,896 B
    __shared__ __align__(16) unsigned short xb[2][32 * 136];        // 17,408 B

    const int tid = threadIdx.x;
    const int lane = tid & 63;
    const int w = tid >> 6;                 // wave 0..15
    const bool isS = (w < 8);               // S-group: waves 0-7 (GEMM2 side)
    const int gG = w - 8;                   // G-wave id 0..7 (GEMM1 side)
    const int fr = lane & 15;
    const int fo8 = (lane >> 4) * 8;
    const int qr = (lane >> 4) * 4;
    const int b = blockIdx.y;
    const int t0 = blockIdx.x * 256;
    const int s0 = (blockIdx.x == 0) ? 4 : 0;

    const float* __restrict__ xbase = X + (size_t)b * 2048 * 128;
    float* __restrict__ obase = out + (size_t)b * 2048 * 128;

    // ---- weight fragments (same split8 values/order as R0) ----
    half8 wf[16];
    float bias0[2];
    if (isS) {
        // W2 col-block: d-row 16w+fr; wf[ks*2+p]
        const size_t d = (size_t)(16 * w + fr) * 256;
#pragma unroll
        for (int ks = 0; ks < 8; ++ks) {
            float4 f0 = *(const float4*)&W2[d + ks * 32 + fo8];
            float4 f1 = *(const float4*)&W2[d + ks * 32 + fo8 + 4];
            split8(f0, f1, wf[ks * 2], wf[ks * 2 + 1]);
        }
        bias0[0] = b2[16 * w + fr];
    } else {
        // W1 col-blocks: h-rows 32gG+16j+fr, j<2; wf[(j*4+k0)*2+p]
#pragma unroll
        for (int j = 0; j < 2; ++j) {
            const size_t n = (size_t)(32 * gG + 16 * j + fr) * 128;
#pragma unroll
            for (int k0 = 0; k0 < 4; ++k0) {
                float4 f0 = *(const float4*)&W1[n + k0 * 32 + fo8];
                float4 f1 = *(const float4*)&W1[n + k0 * 32 + fo8 + 4];
                split8(f0, f1, wf[(j * 4 + k0) * 2], wf[(j * 4 + k0) * 2 + 1]);
            }
            bias0[j] = b1[32 * gG + 16 * j + fr];
        }
    }
    const float2 wv = *(const float2*)(lnw + lane * 2);
    const float2 bbv = *(const float2*)(lnb + lane * 2);

    float v1 = 0.0f, v2 = 0.0f;
    const int d2 = (tid - 256) & 127;       // scan2 col (tid in [256,384))
    const int tgs = (tid - 384) & 127;      // stage thread idx (tid in [384,512))
    const int srow = tgs >> 5;              // 0..3
    const int sc4 = (tgs & 31) * 4;         // 0..124
    const bool isStage = (tid >= 384 && tid < 512);
    float4 pfx[8];
    float2 pflnC[2], pflnN[2];

    // ---- prologue: stage x(s0); GEMM1(s0); prime pfx for x(s0+1) ----
    if (isStage) {
        const int tb = t0 - 128 + s0 * 32;
#pragma unroll
        for (int q = 0; q < 8; ++q) {
            float4 xv = *(const float4*)&xbase[(size_t)(tb + srow + 4 * q) * 128 + sc4];
            _Float16 a0 = (_Float16)xv.x, e0 = (_Float16)(xv.x - (float)a0);
            _Float16 a1 = (_Float16)xv.y, e1 = (_Float16)(xv.y - (float)a1);
            _Float16 a2 = (_Float16)xv.z, e2 = (_Float16)(xv.z - (float)a2);
            _Float16 a3 = (_Float16)xv.w, e3 = (_Float16)(xv.w - (float)a3);
            ushort4 ua = {h2u(a0), h2u(a1), h2u(a2), h2u(a3)};
            ushort4 ue = {h2u(e0), h2u(e1), h2u(e2), h2u(e3)};
            *(ushort4*)&xb[0][(srow + 4 * q) * 136 + sc4] = ua;
            *(ushort4*)&xb[1][(srow + 4 * q) * 136 + sc4] = ue;
        }
    }
    __syncthreads();
    if (!isS) {
        const _Float16* xa0 = (const _Float16*)&xb[0][0];
        const _Float16* xa1 = (const _Float16*)&xb[1][0];
#pragma unroll
        for (int h = 0; h < 2; ++h) {
            f32x4 acc[2];
            acc[0] = (f32x4){0.f, 0.f, 0.f, 0.f};
            acc[1] = (f32x4){0.f, 0.f, 0.f, 0.f};
#pragma unroll
            for (int k0 = 0; k0 < 4; ++k0) {
                half8 a0 = *(const half8*)&xa0[(fr + 16 * h) * 136 + k0 * 32 + fo8];
                half8 a1 = *(const half8*)&xa1[(fr + 16 * h) * 136 + k0 * 32 + fo8];
#pragma unroll
                for (int j = 0; j < 2; ++j) {
                    acc[j] = MFMA_F16(a0, wf[(j * 4 + k0) * 2], acc[j]);
                    acc[j] = MFMA_F16(a0, wf[(j * 4 + k0) * 2 + 1], acc[j]);
                    acc[j] = MFMA_F16(a1, wf[(j * 4 + k0) * 2], acc[j]);
                }
            }
#pragma unroll
            for (int j = 0; j < 2; ++j) {
                int col = 32 * gG + 16 * j + fr;
                float4 o;
                o.x = acc[j][0] + bias0[j];
                o.y = acc[j][1] + bias0[j];
                o.z = acc[j][2] + bias0[j];
                o.w = acc[j][3] + bias0[j];
                *(float4*)&h1T[col * 36 + qr + 16 * h] = o;
            }
        }
    }
    if (isStage) {
        const int tb = t0 - 128 + s0 * 32 + 32;
#pragma unroll
        for (int q = 0; q < 8; ++q)
            pfx[q] = *(const float4*)&xbase[(size_t)(tb + srow + 4 * q) * 128 + sc4];
    }
    __syncthreads();

    // ---- main loop: sc = s0..13 ----
    for (int sc = s0; sc <= 13; ++sc) {
        const int tbase = t0 - 128 + sc * 32;

        // ================= phase B =================
        // LN(sc-2) + store FIRST (stores covered by the scans below)
        if (sc >= 6) {
            const int tbm = tbase - 64;
            const float* s2r = &s2buf[sc & 1][0];
#pragma unroll
            for (int rr = 0; rr < 2; ++rr) {
                int row = 2 * w + rr;
                float2 s2v = *(const float2*)&s2r[row * 132 + lane * 2];
                float y0 = pflnC[rr].x + s2v.x;
                float y1 = pflnC[rr].y + s2v.y;
                float sum = y0 + y1;
                float ss = y0 * y0 + y1 * y1;
#pragma unroll
                for (int off = 32; off > 0; off >>= 1) {
                    sum += __shfl_xor(sum, off, 64);
                    ss  += __shfl_xor(ss, off, 64);
                }
                float mu = sum * (1.0f / 128.0f);
                float var = ss * (1.0f / 128.0f) - mu * mu;
                float inv = rsqrtf(var + 1e-5f);
                float2 o;
                o.x = (y0 - mu) * inv * wv.x + bbv.x;
                o.y = (y1 - mu) * inv * wv.y + bbv.y;
                *(float2*)&obase[(size_t)(tbm + row) * 128 + lane * 2] = o;
            }
        }
        if (tid < 256) {
            if (sc <= 11) {
                // scan1(sc): h1T -> spikes (32 t, vector loads)
                float4 hv[8];
#pragma unroll
                for (int k = 0; k < 8; ++k)
                    hv[k] = *(const float4*)&h1T[tid * 36 + 4 * k];
                __builtin_amdgcn_s_setprio(1);
#pragma unroll
                for (int t = 0; t < 32; ++t) {
                    float hh = (t & 3) == 0 ? hv[t >> 2].x
                             : (t & 3) == 1 ? hv[t >> 2].y
                             : (t & 3) == 2 ? hv[t >> 2].z : hv[t >> 2].w;
                    float h = v1 + (hh - v1) * 0.5f;
                    bool sp = (h >= 1.0f);
                    v1 = sp ? 0.0f : h;
                    spkbuf[t * 264 + tid] = sp ? (unsigned short)0x3C00 : (unsigned short)0;
                }
                __builtin_amdgcn_s_setprio(0);
            }
        } else if (tid < 384) {
            if (sc > s0 && sc <= 12) {
                // scan2(sc-1): h2T -> s2[(sc-1)&1] (32 t, vector loads)
                float* s2w = &s2buf[(sc - 1) & 1][0];
                float4 hv[8];
#pragma unroll
                for (int k = 0; k < 8; ++k)
                    hv[k] = *(const float4*)&h2T[d2 * 36 + 4 * k];
                __builtin_amdgcn_s_setprio(1);
#pragma unroll
                for (int t = 0; t < 32; ++t) {
                    float hh = (t & 3) == 0 ? hv[t >> 2].x
                             : (t & 3) == 1 ? hv[t >> 2].y
                             : (t & 3) == 2 ? hv[t >> 2].z : hv[t >> 2].w;
                    float h = v2 + (hh - v2) * 0.5f;
                    bool sp = (h >= 1.0f);
                    v2 = sp ? 0.0f : h;
                    s2w[t * 132 + d2] = sp ? 1.0f : 0.0f;
                }
                __builtin_amdgcn_s_setprio(0);
            }
        } else if (tid < 512) {
            if (sc <= 10) {
                // stage x(sc+1) from pfx regs (32 rows)
#pragma unroll
                for (int q = 0; q < 8; ++q) {
                    float4 xv = pfx[q];
                    _Float16 a0 = (_Float16)xv.x, e0 = (_Float16)(xv.x - (float)a0);
                    _Float16 a1 = (_Float16)xv.y, e1 = (_Float16)(xv.y - (float)a1);
                    _Float16 a2 = (_Float16)xv.z, e2 = (_Float16)(xv.z - (float)a2);
                    _Float16 a3 = (_Float16)xv.w, e3 = (_Float16)(xv.w - (float)a3);
                    ushort4 ua = {h2u(a0), h2u(a1), h2u(a2), h2u(a3)};
                    ushort4 ue = {h2u(e0), h2u(e1), h2u(e2), h2u(e3)};
                    *(ushort4*)&xb[0][(srow + 4 * q) * 136 + sc4] = ua;
                    *(ushort4*)&xb[1][(srow + 4 * q) * 136 + sc4] = ue;
                }
            }
        }
        __syncthreads();

        // ================= phase A =================
        // prefetch issues FIRST (old by the A-end barrier -> cheap drain)
        if (sc >= 5 && sc <= 12) {
            // pfln for LN(sc-1), consumed in B(sc+1): rows of x(sc-1)
#pragma unroll
            for (int rr = 0; rr < 2; ++rr)
                pflnN[rr] = *(const float2*)&xbase[(size_t)(tbase - 32 + 2 * w + rr) * 128 + lane * 2];
        }
        if (isStage && sc <= 9) {
            // issue pfx x(sc+2) early (consumed in B(sc+1) staging)
#pragma unroll
            for (int q = 0; q < 8; ++q)
                pfx[q] = *(const float4*)&xbase[(size_t)(tbase + 64 + srow + 4 * q) * 128 + sc4];
        }
        if (isS) {
            if (sc <= 11) {
                // GEMM2(sc): spikes @ W2 -> h2T (col 16w+fr; two 16-row halves)
                const _Float16* sp = (const _Float16*)&spkbuf[0];
#pragma unroll
                for (int h = 0; h < 2; ++h) {
                    f32x4 acc = (f32x4){0.f, 0.f, 0.f, 0.f};
#pragma unroll
                    for (int ks = 0; ks < 8; ++ks) {
                        half8 a = *(const half8*)&sp[(fr + 16 * h) * 264 + ks * 32 + fo8];
                        acc = MFMA_F16(a, wf[ks * 2], acc);
                        acc = MFMA_F16(a, wf[ks * 2 + 1], acc);
                    }
                    int col = 16 * w + fr;
                    float4 o;
                    o.x = acc[0] + bias0[0];
                    o.y = acc[1] + bias0[0];
                    o.z = acc[2] + bias0[0];
                    o.w = acc[3] + bias0[0];
                    *(float4*)&h2T[col * 36 + qr + 16 * h] = o;
                }
            }
        } else {
            if (sc <= 10) {
                // GEMM1(sc+1): x(sc+1) @ W1 -> h1T (cols 32gG+16j+fr)
                const _Float16* xa0 = (const _Float16*)&xb[0][0];
                const _Float16* xa1 = (const _Float16*)&xb[1][0];
#pragma unroll
                for (int h = 0; h < 2; ++h) {
                    f32x4 acc[2];
                    acc[0] = (f32x4){0.f, 0.f, 0.f, 0.f};
                    acc[1] = (f32x4){0.f, 0.f, 0.f, 0.f};
#pragma unroll
                    for (int k0 = 0; k0 < 4; ++k0) {
                        half8 a0 = *(const half8*)&xa0[(fr + 16 * h) * 136 + k0 * 32 + fo8];
                        half8 a1 = *(const half8*)&xa1[(fr + 16 * h) * 136 + k0 * 32 + fo8];
#pragma unroll
                        for (int j = 0; j < 2; ++j) {
                            acc[j] = MFMA_F16(a0, wf[(j * 4 + k0) * 2], acc[j]);
                            acc[j] = MFMA_F16(a0, wf[(j * 4 + k0) * 2 + 1], acc[j]);
                            acc[j] = MFMA_F16(a1, wf[(j * 4 + k0) * 2], acc[j]);
                        }
                    }
#pragma unroll
                    for (int j = 0; j < 2; ++j) {
                        int col = 32 * gG + 16 * j + fr;
                        float4 o;
                        o.x = acc[j][0] + bias0[j];
                        o.y = acc[j][1] + bias0[j];
                        o.z = acc[j][2] + bias0[j];
                        o.w = acc[j][3] + bias0[j];
                        *(float4*)&h1T[col * 36 + qr + 16 * h] = o;
                    }
                }
            }
        }
#pragma unroll
        for (int rr = 0; rr < 2; ++rr) pflnC[rr] = pflnN[rr];
        __syncthreads();
    }
}

extern "C" void kernel_launch(void* const* d_in, const int* in_sizes, int n_in,
                              void* d_out, int out_size, void* d_ws, size_t ws_size,
                              hipStream_t stream)
{
    const float* x   = (const float*)d_in[0];
    const float* W1  = (const float*)d_in[1];
    const float* b1  = (const float*)d_in[2];
    const float* W2  = (const float*)d_in[3];
    const float* b2  = (const float*)d_in[4];
    const float* lnw = (const float*)d_in[5];
    const float* lnb = (const float*)d_in[6];
    float* out = (float*)d_out;

    dim3 gM(8, 32);   // 256 blocks, 1/CU
    mega_kernel<<<gM, 1024, 0, stream>>>(x, W1, W2, b1, b2, lnw, lnb, out);
}

// Round 11
// 278.729 us; speedup vs baseline: 1.0665x; 1.0665x over previous
//
#include <hip/hip_runtime.h>

// B=32, T=2048, D=128, H=256. fp32 in/out. SINGLE dispatch.
// 2-phase, 2-barrier wave-specialized megakernel, grid (8,32), 1024 threads.
// Chunk = 256 t (finer T-chunking fails numerically), warmup = 128 t,
// subchunk = 32 t, 13 iterations (+1 epilogue).
// KEY CHANGE vs R10 (anti-spill):
//  - amdgpu_waves_per_eu(4,4): pin register budget to exactly 4 waves/EU
//    (128 unified VGPR+AGPR per wave; 16-wave block at 1 block/CU).
//  - scans load h-values in TWO halves of 4x float4 (peak 16 arch-VGPR
//    instead of 32; loads-only change, scan arithmetic order unchanged ->
//    bit-exact). R9/R10 spilled (~500 MB FETCH) because arch-VGPR demand
//    (hv 32 + pfx 32 + temps) exceeded the ~64 arch half of the budget.
// Work partition (bit-exact vs R0 accumulation orders, absmax 0.015625):
//   GEMM2: 8 S-waves (w0-7) x 1 col-block (col 16w+fr), per-col ks/plane order
//   GEMM1: 8 G-waves (w8-15) x 2 col-blocks (col 32gG+16j+fr), k0/plane order
//   scan1 tid<256 / scan2 tid in [256,384) / stage tid in [384,512)
//   LN: 32 rows over 16 waves (2 rows/wave), per-row math identical
//
// LDS 123,392 B (<= 160 KiB; 1 block/CU):
//   h1T[256*36] f32 (36,864)  h2T[128*36] f32 (18,432)
//   s2buf[2][32*132] f32 (33,792)  spkbuf[32*264] fp16 (16,896)
//   xb[2][32*136] fp16 (17,408)

typedef _Float16 half8 __attribute__((ext_vector_type(8)));
typedef float f32x4 __attribute__((ext_vector_type(4)));

#define MFMA_F16(a, b, c) __builtin_amdgcn_mfma_f32_16x16x32_f16(a, b, c, 0, 0, 0)

__device__ __forceinline__ unsigned short h2u(_Float16 h) {
    union { _Float16 h; unsigned short u; } x; x.h = h; return x.u;
}

__device__ __forceinline__ void split8(float4 f0, float4 f1, half8& a, half8& b) {
    float fs[8] = {f0.x, f0.y, f0.z, f0.w, f1.x, f1.y, f1.z, f1.w};
    half8 ha, hb;
#pragma unroll
    for (int q = 0; q < 8; ++q) {
        ha[q] = (_Float16)fs[q];
        hb[q] = (_Float16)(fs[q] - (float)ha[q]);
    }
    a = ha; b = hb;
}

__attribute__((amdgpu_waves_per_eu(4, 4)))
__global__ __launch_bounds__(1024) void mega_kernel(
    const float* __restrict__ X,
    const float* __restrict__ W1, const float* __restrict__ W2,
    const float* __restrict__ b1, const float* __restrict__ b2,
    const float* __restrict__ lnw, const float* __restrict__ lnb,
    float* __restrict__ out)
{
    __shared__ __align__(16) float h1T[256 * 36];                   // 36,864 B
    __shared__ __align__(16) float h2T[128 * 36];                   // 18,432 B
    __shared__ __align__(16) float s2buf[2][32 * 132];              // 33,792 B
    __shared__ __align__(16) unsigned short spkbuf[32 * 264];       // 16,896 B
    __shared__ __align__(16) unsigned short xb[2][32 * 136];        // 17,408 B

    const int tid = threadIdx.x;
    const int lane = tid & 63;
    const int w = tid >> 6;                 // wave 0..15
    const bool isS = (w < 8);               // S-group: waves 0-7 (GEMM2 side)
    const int gG = w - 8;                   // G-wave id 0..7 (GEMM1 side)
    const int fr = lane & 15;
    const int fo8 = (lane >> 4) * 8;
    const int qr = (lane >> 4) * 4;
    const int b = blockIdx.y;
    const int t0 = blockIdx.x * 256;
    const int s0 = (blockIdx.x == 0) ? 4 : 0;

    const float* __restrict__ xbase = X + (size_t)b * 2048 * 128;
    float* __restrict__ obase = out + (size_t)b * 2048 * 128;

    // ---- weight fragments (same split8 values/order as R0) ----
    half8 wf[16];
    float bias0[2];
    if (isS) {
        // W2 col-block: d-row 16w+fr; wf[ks*2+p]
        const size_t d = (size_t)(16 * w + fr) * 256;
#pragma unroll
        for (int ks = 0; ks < 8; ++ks) {
            float4 f0 = *(const float4*)&W2[d + ks * 32 + fo8];
            float4 f1 = *(const float4*)&W2[d + ks * 32 + fo8 + 4];
            split8(f0, f1, wf[ks * 2], wf[ks * 2 + 1]);
        }
        bias0[0] = b2[16 * w + fr];
    } else {
        // W1 col-blocks: h-rows 32gG+16j+fr, j<2; wf[(j*4+k0)*2+p]
#pragma unroll
        for (int j = 0; j < 2; ++j) {
            const size_t n = (size_t)(32 * gG + 16 * j + fr) * 128;
#pragma unroll
            for (int k0 = 0; k0 < 4; ++k0) {
                float4 f0 = *(const float4*)&W1[n + k0 * 32 + fo8];
                float4 f1 = *(const float4*)&W1[n + k0 * 32 + fo8 + 4];
                split8(f0, f1, wf[(j * 4 + k0) * 2], wf[(j * 4 + k0) * 2 + 1]);
            }
            bias0[j] = b1[32 * gG + 16 * j + fr];
        }
    }
    const float2 wv = *(const float2*)(lnw + lane * 2);
    const float2 bbv = *(const float2*)(lnb + lane * 2);

    float v1 = 0.0f, v2 = 0.0f;
    const int d2 = (tid - 256) & 127;       // scan2 col (tid in [256,384))
    const int tgs = (tid - 384) & 127;      // stage thread idx (tid in [384,512))
    const int srow = tgs >> 5;              // 0..3
    const int sc4 = (tgs & 31) * 4;         // 0..124
    const bool isStage = (tid >= 384 && tid < 512);
    float4 pfx[8];
    float2 pflnC[2], pflnN[2];

    // ---- prologue: stage x(s0); GEMM1(s0); prime pfx for x(s0+1) ----
    if (isStage) {
        const int tb = t0 - 128 + s0 * 32;
#pragma unroll
        for (int q = 0; q < 8; ++q) {
            float4 xv = *(const float4*)&xbase[(size_t)(tb + srow + 4 * q) * 128 + sc4];
            _Float16 a0 = (_Float16)xv.x, e0 = (_Float16)(xv.x - (float)a0);
            _Float16 a1 = (_Float16)xv.y, e1 = (_Float16)(xv.y - (float)a1);
            _Float16 a2 = (_Float16)xv.z, e2 = (_Float16)(xv.z - (float)a2);
            _Float16 a3 = (_Float16)xv.w, e3 = (_Float16)(xv.w - (float)a3);
            ushort4 ua = {h2u(a0), h2u(a1), h2u(a2), h2u(a3)};
            ushort4 ue = {h2u(e0), h2u(e1), h2u(e2), h2u(e3)};
            *(ushort4*)&xb[0][(srow + 4 * q) * 136 + sc4] = ua;
            *(ushort4*)&xb[1][(srow + 4 * q) * 136 + sc4] = ue;
        }
    }
    __syncthreads();
    if (!isS) {
        const _Float16* xa0 = (const _Float16*)&xb[0][0];
        const _Float16* xa1 = (const _Float16*)&xb[1][0];
#pragma unroll
        for (int h = 0; h < 2; ++h) {
            f32x4 acc[2];
            acc[0] = (f32x4){0.f, 0.f, 0.f, 0.f};
            acc[1] = (f32x4){0.f, 0.f, 0.f, 0.f};
#pragma unroll
            for (int k0 = 0; k0 < 4; ++k0) {
                half8 a0 = *(const half8*)&xa0[(fr + 16 * h) * 136 + k0 * 32 + fo8];
                half8 a1 = *(const half8*)&xa1[(fr + 16 * h) * 136 + k0 * 32 + fo8];
#pragma unroll
                for (int j = 0; j < 2; ++j) {
                    acc[j] = MFMA_F16(a0, wf[(j * 4 + k0) * 2], acc[j]);
                    acc[j] = MFMA_F16(a0, wf[(j * 4 + k0) * 2 + 1], acc[j]);
                    acc[j] = MFMA_F16(a1, wf[(j * 4 + k0) * 2], acc[j]);
                }
            }
#pragma unroll
            for (int j = 0; j < 2; ++j) {
                int col = 32 * gG + 16 * j + fr;
                float4 o;
                o.x = acc[j][0] + bias0[j];
                o.y = acc[j][1] + bias0[j];
                o.z = acc[j][2] + bias0[j];
                o.w = acc[j][3] + bias0[j];
                *(float4*)&h1T[col * 36 + qr + 16 * h] = o;
            }
        }
    }
    if (isStage) {
        const int tb = t0 - 128 + s0 * 32 + 32;
#pragma unroll
        for (int q = 0; q < 8; ++q)
            pfx[q] = *(const float4*)&xbase[(size_t)(tb + srow + 4 * q) * 128 + sc4];
    }
    __syncthreads();

    // ---- main loop: sc = s0..13 ----
    for (int sc = s0; sc <= 13; ++sc) {
        const int tbase = t0 - 128 + sc * 32;

        // ================= phase B =================
        // LN(sc-2) + store FIRST (stores covered by the scans below)
        if (sc >= 6) {
            const int tbm = tbase - 64;
            const float* s2r = &s2buf[sc & 1][0];
#pragma unroll
            for (int rr = 0; rr < 2; ++rr) {
                int row = 2 * w + rr;
                float2 s2v = *(const float2*)&s2r[row * 132 + lane * 2];
                float y0 = pflnC[rr].x + s2v.x;
                float y1 = pflnC[rr].y + s2v.y;
                float sum = y0 + y1;
                float ss = y0 * y0 + y1 * y1;
#pragma unroll
                for (int off = 32; off > 0; off >>= 1) {
                    sum += __shfl_xor(sum, off, 64);
                    ss  += __shfl_xor(ss, off, 64);
                }
                float mu = sum * (1.0f / 128.0f);
                float var = ss * (1.0f / 128.0f) - mu * mu;
                float inv = rsqrtf(var + 1e-5f);
                float2 o;
                o.x = (y0 - mu) * inv * wv.x + bbv.x;
                o.y = (y1 - mu) * inv * wv.y + bbv.y;
                *(float2*)&obase[(size_t)(tbm + row) * 128 + lane * 2] = o;
            }
        }
        if (tid < 256) {
            if (sc <= 11) {
                // scan1(sc): h1T -> spikes; h loaded in 2 halves (16 regs peak)
                __builtin_amdgcn_s_setprio(1);
#pragma unroll
                for (int half = 0; half < 2; ++half) {
                    float4 hv[4];
#pragma unroll
                    for (int k = 0; k < 4; ++k)
                        hv[k] = *(const float4*)&h1T[tid * 36 + 16 * half + 4 * k];
#pragma unroll
                    for (int tt = 0; tt < 16; ++tt) {
                        int t = 16 * half + tt;
                        float hh = (tt & 3) == 0 ? hv[tt >> 2].x
                                 : (tt & 3) == 1 ? hv[tt >> 2].y
                                 : (tt & 3) == 2 ? hv[tt >> 2].z : hv[tt >> 2].w;
                        float h = v1 + (hh - v1) * 0.5f;
                        bool sp = (h >= 1.0f);
                        v1 = sp ? 0.0f : h;
                        spkbuf[t * 264 + tid] = sp ? (unsigned short)0x3C00 : (unsigned short)0;
                    }
                }
                __builtin_amdgcn_s_setprio(0);
            }
        } else if (tid < 384) {
            if (sc > s0 && sc <= 12) {
                // scan2(sc-1): h2T -> s2[(sc-1)&1]; 2 halves (16 regs peak)
                float* s2w = &s2buf[(sc - 1) & 1][0];
                __builtin_amdgcn_s_setprio(1);
#pragma unroll
                for (int half = 0; half < 2; ++half) {
                    float4 hv[4];
#pragma unroll
                    for (int k = 0; k < 4; ++k)
                        hv[k] = *(const float4*)&h2T[d2 * 36 + 16 * half + 4 * k];
#pragma unroll
                    for (int tt = 0; tt < 16; ++tt) {
                        int t = 16 * half + tt;
                        float hh = (tt & 3) == 0 ? hv[tt >> 2].x
                                 : (tt & 3) == 1 ? hv[tt >> 2].y
                                 : (tt & 3) == 2 ? hv[tt >> 2].z : hv[tt >> 2].w;
                        float h = v2 + (hh - v2) * 0.5f;
                        bool sp = (h >= 1.0f);
                        v2 = sp ? 0.0f : h;
                        s2w[t * 132 + d2] = sp ? 1.0f : 0.0f;
                    }
                }
                __builtin_amdgcn_s_setprio(0);
            }
        } else if (tid < 512) {
            if (sc <= 10) {
                // stage x(sc+1) from pfx regs (32 rows)
#pragma unroll
                for (int q = 0; q < 8; ++q) {
                    float4 xv = pfx[q];
                    _Float16 a0 = (_Float16)xv.x, e0 = (_Float16)(xv.x - (float)a0);
                    _Float16 a1 = (_Float16)xv.y, e1 = (_Float16)(xv.y - (float)a1);
                    _Float16 a2 = (_Float16)xv.z, e2 = (_Float16)(xv.z - (float)a2);
                    _Float16 a3 = (_Float16)xv.w, e3 = (_Float16)(xv.w - (float)a3);
                    ushort4 ua = {h2u(a0), h2u(a1), h2u(a2), h2u(a3)};
                    ushort4 ue = {h2u(e0), h2u(e1), h2u(e2), h2u(e3)};
                    *(ushort4*)&xb[0][(srow + 4 * q) * 136 + sc4] = ua;
                    *(ushort4*)&xb[1][(srow + 4 * q) * 136 + sc4] = ue;
                }
            }
        }
        __syncthreads();

        // ================= phase A =================
        // prefetch issues FIRST (old by the A-end barrier -> cheap drain)
        if (sc >= 5 && sc <= 12) {
            // pfln for LN(sc-1), consumed in B(sc+1): rows of x(sc-1)
#pragma unroll
            for (int rr = 0; rr < 2; ++rr)
                pflnN[rr] = *(const float2*)&xbase[(size_t)(tbase - 32 + 2 * w + rr) * 128 + lane * 2];
        }
        if (isStage && sc <= 9) {
            // issue pfx x(sc+2) early (consumed in B(sc+1) staging)
#pragma unroll
            for (int q = 0; q < 8; ++q)
                pfx[q] = *(const float4*)&xbase[(size_t)(tbase + 64 + srow + 4 * q) * 128 + sc4];
        }
        if (isS) {
            if (sc <= 11) {
                // GEMM2(sc): spikes @ W2 -> h2T (col 16w+fr; two 16-row halves)
                const _Float16* sp = (const _Float16*)&spkbuf[0];
#pragma unroll
                for (int h = 0; h < 2; ++h) {
                    f32x4 acc = (f32x4){0.f, 0.f, 0.f, 0.f};
#pragma unroll
                    for (int ks = 0; ks < 8; ++ks) {
                        half8 a = *(const half8*)&sp[(fr + 16 * h) * 264 + ks * 32 + fo8];
                        acc = MFMA_F16(a, wf[ks * 2], acc);
                        acc = MFMA_F16(a, wf[ks * 2 + 1], acc);
                    }
                    int col = 16 * w + fr;
                    float4 o;
                    o.x = acc[0] + bias0[0];
                    o.y = acc[1] + bias0[0];
                    o.z = acc[2] + bias0[0];
                    o.w = acc[3] + bias0[0];
                    *(float4*)&h2T[col * 36 + qr + 16 * h] = o;
                }
            }
        } else {
            if (sc <= 10) {
                // GEMM1(sc+1): x(sc+1) @ W1 -> h1T (cols 32gG+16j+fr)
                const _Float16* xa0 = (const _Float16*)&xb[0][0];
                const _Float16* xa1 = (const _Float16*)&xb[1][0];
#pragma unroll
                for (int h = 0; h < 2; ++h) {
                    f32x4 acc[2];
                    acc[0] = (f32x4){0.f, 0.f, 0.f, 0.f};
                    acc[1] = (f32x4){0.f, 0.f, 0.f, 0.f};
#pragma unroll
                    for (int k0 = 0; k0 < 4; ++k0) {
                        half8 a0 = *(const half8*)&xa0[(fr + 16 * h) * 136 + k0 * 32 + fo8];
                        half8 a1 = *(const half8*)&xa1[(fr + 16 * h) * 136 + k0 * 32 + fo8];
#pragma unroll
                        for (int j = 0; j < 2; ++j) {
                            acc[j] = MFMA_F16(a0, wf[(j * 4 + k0) * 2], acc[j]);
                            acc[j] = MFMA_F16(a0, wf[(j * 4 + k0) * 2 + 1], acc[j]);
                            acc[j] = MFMA_F16(a1, wf[(j * 4 + k0) * 2], acc[j]);
                        }
                    }
#pragma unroll
                    for (int j = 0; j < 2; ++j) {
                        int col = 32 * gG + 16 * j + fr;
                        float4 o;
                        o.x = acc[j][0] + bias0[j];
                        o.y = acc[j][1] + bias0[j];
                        o.z = acc[j][2] + bias0[j];
                        o.w = acc[j][3] + bias0[j];
                        *(float4*)&h1T[col * 36 + qr + 16 * h] = o;
                    }
                }
            }
        }
#pragma unroll
        for (int rr = 0; rr < 2; ++rr) pflnC[rr] = pflnN[rr];
        __syncthreads();
    }
}

extern "C" void kernel_launch(void* const* d_in, const int* in_sizes, int n_in,
                              void* d_out, int out_size, void* d_ws, size_t ws_size,
                              hipStream_t stream)
{
    const float* x   = (const float*)d_in[0];
    const float* W1  = (const float*)d_in[1];
    const float* b1  = (const float*)d_in[2];
    const float* W2  = (const float*)d_in[3];
    const float* b2  = (const float*)d_in[4];
    const float* lnw = (const float*)d_in[5];
    const float* lnb = (const float*)d_in[6];
    float* out = (float*)d_out;

    dim3 gM(8, 32);   // 256 blocks, 1/CU
    mega_kernel<<<gM, 1024, 0, stream>>>(x, W1, W2, b1, b2, lnw, lnb, out);
}

// Round 12
// 146.716 us; speedup vs baseline: 2.0261x; 1.8998x over previous
//
#include <hip/hip_runtime.h>

// B=32, T=2048, D=128, H=256. fp32 in/out. SINGLE dispatch.
// SINGLE-PHASE, 1-barrier-per-iteration pipelined megakernel, grid (8,32),
// 512 threads (8 waves, 2/SIMD -- register ceiling: wf 128 + prefetch ~40
// caps at 2 waves/SIMD; R9-R11 proved 3-4 waves/SIMD spills).
// Chunk = 256 t, warmup = 128 t, subchunk = 16 t.
// All five LDS buffers parity double-buffered; per phase p (1 barrier):
//   S-waves 0-3 : GEMM2(p-1): spk[(p-1)&1] -> h2[(p-1)&1]
//                 scan1(p):   h1[p&1] -> spk[p&1]
//   waves 6-7   : stage(p+2): pfx regs -> xb[p&1]; reissue pfx x(p+4)
//   G-waves 4-7 : GEMM1(p+1): xb[(p+1)&1] -> h1[(p+1)&1]
//   waves 4-5   : scan2(p-2): h2[(p-2)&1] -> s2[(p-2)&1]
//   all         : pfln issue x(p-2); LN(p-3): s2[(p-3)&1] + pflnC -> out
// Hazard audit: every same-phase read/write pair targets opposite parities;
// every overwrite is 2 phases after the write, 1 barrier after last read.
// All sub-op code blocks verbatim from the proven R3 16-t kernel (same
// accumulation orders) -> absmax 0.015625.
//
// LDS 101,376 B:
//   h1[2][16*260] f32 (33,280)  h2[2][16*132] f32 (16,896)
//   s2[2][16*132] f32 (16,896)  spk[2][16*264] fp16 (16,896)
//   xb[2][2][16*136] fp16 (17,408)

typedef _Float16 half8 __attribute__((ext_vector_type(8)));
typedef float f32x4 __attribute__((ext_vector_type(4)));

#define MFMA_F16(a, b, c) __builtin_amdgcn_mfma_f32_16x16x32_f16(a, b, c, 0, 0, 0)

__device__ __forceinline__ unsigned short h2u(_Float16 h) {
    union { _Float16 h; unsigned short u; } x; x.h = h; return x.u;
}

__device__ __forceinline__ void split8(float4 f0, float4 f1, half8& a, half8& b) {
    float fs[8] = {f0.x, f0.y, f0.z, f0.w, f1.x, f1.y, f1.z, f1.w};
    half8 ha, hb;
#pragma unroll
    for (int q = 0; q < 8; ++q) {
        ha[q] = (_Float16)fs[q];
        hb[q] = (_Float16)(fs[q] - (float)ha[q]);
    }
    a = ha; b = hb;
}

__global__ __launch_bounds__(512, 1) void mega_kernel(
    const float* __restrict__ X,
    const float* __restrict__ W1, const float* __restrict__ W2,
    const float* __restrict__ b1, const float* __restrict__ b2,
    const float* __restrict__ lnw, const float* __restrict__ lnb,
    float* __restrict__ out)
{
    __shared__ __align__(16) float h1[2][16 * 260];                 // 33,280 B
    __shared__ __align__(16) float h2[2][16 * 132];                 // 16,896 B
    __shared__ __align__(16) float s2[2][16 * 132];                 // 16,896 B
    __shared__ __align__(16) unsigned short spk[2][16 * 264];       // 16,896 B
    __shared__ __align__(16) unsigned short xb[2][2][16 * 136];     // 17,408 B

    const int tid = threadIdx.x;
    const int lane = tid & 63;
    const int w = tid >> 6;                 // wave 0..7
    const bool isS = (tid < 256);           // S-group: waves 0-3
    const int sg = w;                       // S-wave id
    const int gg = w - 4;                   // G-wave id
    const int fr = lane & 15;
    const int fo8 = (lane >> 4) * 8;
    const int qr = (lane >> 4) * 4;
    const int b = blockIdx.y;
    const int t0 = blockIdx.x * 256;
    const int s0 = (blockIdx.x == 0) ? 8 : 0;   // always even

    const float* __restrict__ xbase = X + (size_t)b * 2048 * 128;
    float* __restrict__ obase = out + (size_t)b * 2048 * 128;

    // ---- shared-physical weight fragments (identical to R0) ----
    half8 wf[32];
    float bias0[4];
    if (isS) {
        // W2 slice: d-rows 32sg+16j+fr, j<2; wf[(j*8+ks)*2+p]
#pragma unroll
        for (int j = 0; j < 2; ++j) {
            const size_t d = (size_t)(32 * sg + 16 * j + fr) * 256;
#pragma unroll
            for (int ks = 0; ks < 8; ++ks) {
                float4 f0 = *(const float4*)&W2[d + ks * 32 + fo8];
                float4 f1 = *(const float4*)&W2[d + ks * 32 + fo8 + 4];
                split8(f0, f1, wf[(j * 8 + ks) * 2], wf[(j * 8 + ks) * 2 + 1]);
            }
            bias0[j] = b2[32 * sg + 16 * j + fr];
        }
    } else {
        // W1 slice: h-rows 64gg+16j+fr, j<4; wf[(j*4+k0)*2+p]
#pragma unroll
        for (int j = 0; j < 4; ++j) {
            const size_t n = (size_t)(64 * gg + 16 * j + fr) * 128;
#pragma unroll
            for (int k0 = 0; k0 < 4; ++k0) {
                float4 f0 = *(const float4*)&W1[n + k0 * 32 + fo8];
                float4 f1 = *(const float4*)&W1[n + k0 * 32 + fo8 + 4];
                split8(f0, f1, wf[(j * 4 + k0) * 2], wf[(j * 4 + k0) * 2 + 1]);
            }
            bias0[j] = b1[64 * gg + 16 * j + fr];
        }
    }
    const float2 wv = *(const float2*)(lnw + lane * 2);
    const float2 bbv = *(const float2*)(lnb + lane * 2);

    float v1 = 0.0f, v2 = 0.0f;
    const int d2 = (tid - 256) & 127;       // scan2 col (waves 4-5)
    const int tgs = (tid - 384) & 127;      // stage thread idx (waves 6-7)
    const int srow = tgs >> 5;              // 0..3
    const int sc4 = (tgs & 31) * 4;         // 0..124
    const bool isStage = (tid >= 384);
    float4 pfxA[4], pfxB[4];                // pfx sets for even/odd target parity
    float2 pflnC[2], pflnN[2];

    // helper lambda: convert+write one subchunk row set into xb[par]
    auto stage_write = [&](int par, const float4 (&pf)[4]) {
#pragma unroll
        for (int q = 0; q < 4; ++q) {
            float4 xv = pf[q];
            _Float16 a0 = (_Float16)xv.x, e0 = (_Float16)(xv.x - (float)a0);
            _Float16 a1 = (_Float16)xv.y, e1 = (_Float16)(xv.y - (float)a1);
            _Float16 a2 = (_Float16)xv.z, e2 = (_Float16)(xv.z - (float)a2);
            _Float16 a3 = (_Float16)xv.w, e3 = (_Float16)(xv.w - (float)a3);
            ushort4 ua = {h2u(a0), h2u(a1), h2u(a2), h2u(a3)};
            ushort4 ue = {h2u(e0), h2u(e1), h2u(e2), h2u(e3)};
            *(ushort4*)&xb[par][0][(srow + 4 * q) * 136 + sc4] = ua;
            *(ushort4*)&xb[par][1][(srow + 4 * q) * 136 + sc4] = ue;
        }
    };

    // ---- prologue ----
    // stage xb(s0) direct
    if (isStage) {
        const int tb = t0 - 128 + s0 * 16;
        float4 pf[4];
#pragma unroll
        for (int q = 0; q < 4; ++q)
            pf[q] = *(const float4*)&xbase[(size_t)(tb + srow + 4 * q) * 128 + sc4];
        stage_write(s0 & 1, pf);
    }
    __syncthreads();
    if (!isS) {
        // GEMM1(s0) -> h1[s0&1]
        const _Float16* xa0 = (const _Float16*)&xb[s0 & 1][0][0];
        const _Float16* xa1 = (const _Float16*)&xb[s0 & 1][1][0];
        f32x4 acc[4];
#pragma unroll
        for (int j = 0; j < 4; ++j) acc[j] = (f32x4){0.f, 0.f, 0.f, 0.f};
#pragma unroll
        for (int k0 = 0; k0 < 4; ++k0) {
            half8 a0 = *(const half8*)&xa0[fr * 136 + k0 * 32 + fo8];
            half8 a1 = *(const half8*)&xa1[fr * 136 + k0 * 32 + fo8];
#pragma unroll
            for (int j = 0; j < 4; ++j) {
                acc[j] = MFMA_F16(a0, wf[(j * 4 + k0) * 2], acc[j]);
                acc[j] = MFMA_F16(a0, wf[(j * 4 + k0) * 2 + 1], acc[j]);
                acc[j] = MFMA_F16(a1, wf[(j * 4 + k0) * 2], acc[j]);
            }
        }
#pragma unroll
        for (int j = 0; j < 4; ++j) {
            int col = 64 * gg + 16 * j + fr;
#pragma unroll
            for (int r = 0; r < 4; ++r)
                h1[s0 & 1][(qr + r) * 260 + col] = acc[j][r] + bias0[j];
        }
        if (isStage) {
            // stage xb(s0+1) direct (opposite parity)
            const int tb1 = t0 - 128 + (s0 + 1) * 16;
            float4 pf[4];
#pragma unroll
            for (int q = 0; q < 4; ++q)
                pf[q] = *(const float4*)&xbase[(size_t)(tb1 + srow + 4 * q) * 128 + sc4];
            stage_write((s0 + 1) & 1, pf);
            // prime pfx: A (even parity target) = x(s0+2), B = x(s0+3)
            const int tb2 = t0 - 128 + (s0 + 2) * 16;
            const int tb3 = t0 - 128 + (s0 + 3) * 16;
#pragma unroll
            for (int q = 0; q < 4; ++q) {
                pfxA[q] = *(const float4*)&xbase[(size_t)(tb2 + srow + 4 * q) * 128 + sc4];
                pfxB[q] = *(const float4*)&xbase[(size_t)(tb3 + srow + 4 * q) * 128 + sc4];
            }
        }
    }
    __syncthreads();

    // ---- main loop: single phase, single barrier ----
    for (int ph = s0; ph <= 26; ++ph) {
        const int tb = t0 - 128 + ph * 16;

        // pfln issue early: x(ph-2) rows for LN(ph-2) next phase
        if (ph >= 10 && ph <= 25) {
#pragma unroll
            for (int rr = 0; rr < 2; ++rr)
                pflnN[rr] = *(const float2*)&xbase[(size_t)(tb - 32 + 2 * w + rr) * 128 + lane * 2];
        }

        if (isS) {
            // GEMM2(ph-1): spk[(ph-1)&1] -> h2[(ph-1)&1]
            if (ph >= s0 + 1 && ph <= 24) {
                const int p = (ph - 1) & 1;
                const _Float16* sp = (const _Float16*)&spk[p][0];
                f32x4 acc[2];
                acc[0] = (f32x4){0.f, 0.f, 0.f, 0.f};
                acc[1] = (f32x4){0.f, 0.f, 0.f, 0.f};
#pragma unroll
                for (int ks = 0; ks < 8; ++ks) {
                    half8 a = *(const half8*)&sp[fr * 264 + ks * 32 + fo8];
#pragma unroll
                    for (int j = 0; j < 2; ++j) {
                        acc[j] = MFMA_F16(a, wf[(j * 8 + ks) * 2], acc[j]);
                        acc[j] = MFMA_F16(a, wf[(j * 8 + ks) * 2 + 1], acc[j]);
                    }
                }
#pragma unroll
                for (int j = 0; j < 2; ++j) {
                    int col = 32 * sg + 16 * j + fr;
#pragma unroll
                    for (int r = 0; r < 4; ++r)
                        h2[p][(qr + r) * 132 + col] = acc[j][r] + bias0[j];
                }
            }
            // scan1(ph): h1[ph&1] -> spk[ph&1]
            if (ph <= 23) {
                const int p = ph & 1;
                float hh[16];
#pragma unroll
                for (int t = 0; t < 16; ++t) hh[t] = h1[p][t * 260 + tid];
                __builtin_amdgcn_s_setprio(1);
#pragma unroll
                for (int t = 0; t < 16; ++t) {
                    float h = v1 + (hh[t] - v1) * 0.5f;
                    bool sp_ = (h >= 1.0f);
                    v1 = sp_ ? 0.0f : h;
                    spk[p][t * 264 + tid] = sp_ ? (unsigned short)0x3C00 : (unsigned short)0;
                }
                __builtin_amdgcn_s_setprio(0);
            }
        } else {
            // stage(ph+2): pfx set[ph&1] -> xb[ph&1]
            if (isStage && ph <= 21) {
                if ((ph & 1) == 0) stage_write(0, pfxA);
                else               stage_write(1, pfxB);
            }
            // reissue pfx set[ph&1] = x(ph+4)
            if (isStage && ph <= 19) {
                const int tbn = tb + 64;
                if ((ph & 1) == 0) {
#pragma unroll
                    for (int q = 0; q < 4; ++q)
                        pfxA[q] = *(const float4*)&xbase[(size_t)(tbn + srow + 4 * q) * 128 + sc4];
                } else {
#pragma unroll
                    for (int q = 0; q < 4; ++q)
                        pfxB[q] = *(const float4*)&xbase[(size_t)(tbn + srow + 4 * q) * 128 + sc4];
                }
            }
            // GEMM1(ph+1): xb[(ph+1)&1] -> h1[(ph+1)&1]
            if (ph <= 22) {
                const int p = (ph + 1) & 1;
                const _Float16* xa0 = (const _Float16*)&xb[p][0][0];
                const _Float16* xa1 = (const _Float16*)&xb[p][1][0];
                f32x4 acc[4];
#pragma unroll
                for (int j = 0; j < 4; ++j) acc[j] = (f32x4){0.f, 0.f, 0.f, 0.f};
#pragma unroll
                for (int k0 = 0; k0 < 4; ++k0) {
                    half8 a0 = *(const half8*)&xa0[fr * 136 + k0 * 32 + fo8];
                    half8 a1 = *(const half8*)&xa1[fr * 136 + k0 * 32 + fo8];
#pragma unroll
                    for (int j = 0; j < 4; ++j) {
                        acc[j] = MFMA_F16(a0, wf[(j * 4 + k0) * 2], acc[j]);
                        acc[j] = MFMA_F16(a0, wf[(j * 4 + k0) * 2 + 1], acc[j]);
                        acc[j] = MFMA_F16(a1, wf[(j * 4 + k0) * 2], acc[j]);
                    }
                }
#pragma unroll
                for (int j = 0; j < 4; ++j) {
                    int col = 64 * gg + 16 * j + fr;
#pragma unroll
                    for (int r = 0; r < 4; ++r)
                        h1[p][(qr + r) * 260 + col] = acc[j][r] + bias0[j];
                }
            }
            // scan2(ph-2): h2[(ph-2)&1] -> s2[(ph-2)&1]  (waves 4-5)
            if (!isStage && ph >= s0 + 2 && ph <= 25) {
                const int p = (ph - 2) & 1;
                float hh[16];
#pragma unroll
                for (int t = 0; t < 16; ++t) hh[t] = h2[p][t * 132 + d2];
                __builtin_amdgcn_s_setprio(1);
#pragma unroll
                for (int t = 0; t < 16; ++t) {
                    float h = v2 + (hh[t] - v2) * 0.5f;
                    bool sp_ = (h >= 1.0f);
                    v2 = sp_ ? 0.0f : h;
                    s2[p][t * 132 + d2] = sp_ ? 1.0f : 0.0f;
                }
                __builtin_amdgcn_s_setprio(0);
            }
        }

        // LN(ph-3) + store (all 8 waves, 2 rows each)
        if (ph >= 11 && ph <= 26) {
            const int p = (ph - 3) & 1;
            const int tbm = tb - 48;
#pragma unroll
            for (int rr = 0; rr < 2; ++rr) {
                int row = 2 * w + rr;
                float2 s2v = *(const float2*)&s2[p][row * 132 + lane * 2];
                float y0 = pflnC[rr].x + s2v.x;
                float y1 = pflnC[rr].y + s2v.y;
                float sum = y0 + y1;
                float ss = y0 * y0 + y1 * y1;
#pragma unroll
                for (int off = 32; off > 0; off >>= 1) {
                    sum += __shfl_xor(sum, off, 64);
                    ss  += __shfl_xor(ss, off, 64);
                }
                float mu = sum * (1.0f / 128.0f);
                float var = ss * (1.0f / 128.0f) - mu * mu;
                float inv = rsqrtf(var + 1e-5f);
                float2 o;
                o.x = (y0 - mu) * inv * wv.x + bbv.x;
                o.y = (y1 - mu) * inv * wv.y + bbv.y;
                *(float2*)&obase[(size_t)(tbm + row) * 128 + lane * 2] = o;
            }
        }
        pflnC[0] = pflnN[0];
        pflnC[1] = pflnN[1];
        __syncthreads();
    }
}

extern "C" void kernel_launch(void* const* d_in, const int* in_sizes, int n_in,
                              void* d_out, int out_size, void* d_ws, size_t ws_size,
                              hipStream_t stream)
{
    const float* x   = (const float*)d_in[0];
    const float* W1  = (const float*)d_in[1];
    const float* b1  = (const float*)d_in[2];
    const float* W2  = (const float*)d_in[3];
    const float* b2  = (const float*)d_in[4];
    const float* lnw = (const float*)d_in[5];
    const float* lnb = (const float*)d_in[6];
    float* out = (float*)d_out;

    dim3 gM(8, 32);   // 256 blocks, 1/CU
    mega_kernel<<<gM, 512, 0, stream>>>(x, W1, W2, b1, b2, lnw, lnb, out);
}

// Round 13
// 134.732 us; speedup vs baseline: 2.2063x; 1.0889x over previous
//
#include <hip/hip_runtime.h>

// B=32, T=2048, D=128, H=256. fp32 in/out. SINGLE dispatch.
// 2-phase, 2-barrier wave-specialized megakernel, grid (8,32), 512 threads.
// Chunk = 256 t (finer T-chunking fails numerically), warmup = 128 t,
// subchunk = 32 t, 13 iterations (+1 epilogue). Base = R8 (best: 135.25
// bench / ~62.5 us dispatch). Two bit-exact micro-changes:
//  - bar_lds(): raw {s_waitcnt lgkmcnt(0); s_barrier} WITHOUT
//    sched_barrier(0). R4 conflated drain-removal with scheduler pinning
//    (m141-class loss); without the fence, post-barrier ds_reads are ordered
//    by the asm "memory" clobber and register-prefetch uses by compiler
//    vmcnt waits. LN stores + pfx/pfln loads stay in flight across barriers.
//  - s_setprio(1) moved from the scan chains (stalled on VALU latency --
//    priority useless) to the GEMM MFMA clusters (catalog T5 direction).
// Steady state per subchunk sc (32 t):
//   phase B: all: LN(sc-2)+store | scan1(sc) tid<256 | scan2(sc-1) [256,384)
//            | stage x(sc+1) [384,512)
//   bar_lds
//   phase A: all: pfln issue | w6-7: pfx issue x(sc+2)
//            S(w0-3): GEMM2(sc)->h2T | G(w4-7): GEMM1(sc+1)->h1T
//   bar_lds
// All accumulation orders instruction-identical to R0 (absmax 0.015625).
//
// LDS 123,392 B (<= 160 KiB; 1 block/CU):
//   h1T[256*36] f32 (36,864)  h2T[128*36] f32 (18,432)
//   s2buf[2][32*132] f32 (33,792)  spkbuf[32*264] fp16 (16,896)
//   xb[2][32*136] fp16 (17,408)

typedef _Float16 half8 __attribute__((ext_vector_type(8)));
typedef float f32x4 __attribute__((ext_vector_type(4)));

#define MFMA_F16(a, b, c) __builtin_amdgcn_mfma_f32_16x16x32_f16(a, b, c, 0, 0, 0)

__device__ __forceinline__ void bar_lds() {
    // LDS-visibility barrier: drain this wave's DS ops, rendezvous.
    // Does NOT drain vmcnt: LN stores / register prefetches stay in flight.
    asm volatile("s_waitcnt lgkmcnt(0)" ::: "memory");
    __builtin_amdgcn_s_barrier();
}

__device__ __forceinline__ unsigned short h2u(_Float16 h) {
    union { _Float16 h; unsigned short u; } x; x.h = h; return x.u;
}

__device__ __forceinline__ void split8(float4 f0, float4 f1, half8& a, half8& b) {
    float fs[8] = {f0.x, f0.y, f0.z, f0.w, f1.x, f1.y, f1.z, f1.w};
    half8 ha, hb;
#pragma unroll
    for (int q = 0; q < 8; ++q) {
        ha[q] = (_Float16)fs[q];
        hb[q] = (_Float16)(fs[q] - (float)ha[q]);
    }
    a = ha; b = hb;
}

__global__ __launch_bounds__(512, 1) void mega_kernel(
    const float* __restrict__ X,
    const float* __restrict__ W1, const float* __restrict__ W2,
    const float* __restrict__ b1, const float* __restrict__ b2,
    const float* __restrict__ lnw, const float* __restrict__ lnb,
    float* __restrict__ out)
{
    __shared__ __align__(16) float h1T[256 * 36];                   // 36,864 B
    __shared__ __align__(16) float h2T[128 * 36];                   // 18,432 B
    __shared__ __align__(16) float s2buf[2][32 * 132];              // 33,792 B
    __shared__ __align__(16) unsigned short spkbuf[32 * 264];       // 16,896 B
    __shared__ __align__(16) unsigned short xb[2][32 * 136];        // 17,408 B

    const int tid = threadIdx.x;
    const int lane = tid & 63;
    const int w = tid >> 6;                 // wave 0..7
    const bool isS = (tid < 256);           // S-group: waves 0-3
    const int sg = w;                       // S-wave id
    const int gg = w - 4;                   // G-wave id
    const int fr = lane & 15;
    const int fo8 = (lane >> 4) * 8;
    const int qr = (lane >> 4) * 4;
    const int b = blockIdx.y;
    const int t0 = blockIdx.x * 256;
    const int s0 = (blockIdx.x == 0) ? 4 : 0;

    const float* __restrict__ xbase = X + (size_t)b * 2048 * 128;
    float* __restrict__ obase = out + (size_t)b * 2048 * 128;

    // ---- shared-physical weight fragments (identical to R0) ----
    half8 wf[32];
    float bias0[4];
    if (isS) {
        // W2 slice: d-rows 32sg+16j+fr, j<2; wf[(j*8+ks)*2+p]
#pragma unroll
        for (int j = 0; j < 2; ++j) {
            const size_t d = (size_t)(32 * sg + 16 * j + fr) * 256;
#pragma unroll
            for (int ks = 0; ks < 8; ++ks) {
                float4 f0 = *(const float4*)&W2[d + ks * 32 + fo8];
                float4 f1 = *(const float4*)&W2[d + ks * 32 + fo8 + 4];
                split8(f0, f1, wf[(j * 8 + ks) * 2], wf[(j * 8 + ks) * 2 + 1]);
            }
            bias0[j] = b2[32 * sg + 16 * j + fr];
        }
    } else {
        // W1 slice: h-rows 64gg+16j+fr, j<4; wf[(j*4+k0)*2+p]
#pragma unroll
        for (int j = 0; j < 4; ++j) {
            const size_t n = (size_t)(64 * gg + 16 * j + fr) * 128;
#pragma unroll
            for (int k0 = 0; k0 < 4; ++k0) {
                float4 f0 = *(const float4*)&W1[n + k0 * 32 + fo8];
                float4 f1 = *(const float4*)&W1[n + k0 * 32 + fo8 + 4];
                split8(f0, f1, wf[(j * 4 + k0) * 2], wf[(j * 4 + k0) * 2 + 1]);
            }
            bias0[j] = b1[64 * gg + 16 * j + fr];
        }
    }
    const float2 wv = *(const float2*)(lnw + lane * 2);
    const float2 bbv = *(const float2*)(lnb + lane * 2);

    float v1 = 0.0f, v2 = 0.0f;
    const int d2 = (tid - 256) & 127;       // scan2 col (waves 4-5)
    const int tgs = (tid - 384) & 127;      // stage thread idx (waves 6-7)
    const int srow = tgs >> 5;              // 0..3
    const int sc4 = (tgs & 31) * 4;         // 0..124
    float4 pfx[8];
    float2 pflnC[4], pflnN[4];

    // ---- prologue: stage x(s0); GEMM1(s0); prime pfx for x(s0+1) ----
    if (tid >= 384) {
        const int tb = t0 - 128 + s0 * 32;
#pragma unroll
        for (int q = 0; q < 8; ++q) {
            float4 xv = *(const float4*)&xbase[(size_t)(tb + srow + 4 * q) * 128 + sc4];
            _Float16 a0 = (_Float16)xv.x, e0 = (_Float16)(xv.x - (float)a0);
            _Float16 a1 = (_Float16)xv.y, e1 = (_Float16)(xv.y - (float)a1);
            _Float16 a2 = (_Float16)xv.z, e2 = (_Float16)(xv.z - (float)a2);
            _Float16 a3 = (_Float16)xv.w, e3 = (_Float16)(xv.w - (float)a3);
            ushort4 ua = {h2u(a0), h2u(a1), h2u(a2), h2u(a3)};
            ushort4 ue = {h2u(e0), h2u(e1), h2u(e2), h2u(e3)};
            *(ushort4*)&xb[0][(srow + 4 * q) * 136 + sc4] = ua;
            *(ushort4*)&xb[1][(srow + 4 * q) * 136 + sc4] = ue;
        }
    }
    bar_lds();
    if (!isS) {
        const _Float16* xa0 = (const _Float16*)&xb[0][0];
        const _Float16* xa1 = (const _Float16*)&xb[1][0];
#pragma unroll
        for (int h = 0; h < 2; ++h) {
            f32x4 acc[4];
#pragma unroll
            for (int j = 0; j < 4; ++j) acc[j] = (f32x4){0.f, 0.f, 0.f, 0.f};
#pragma unroll
            for (int k0 = 0; k0 < 4; ++k0) {
                half8 a0 = *(const half8*)&xa0[(fr + 16 * h) * 136 + k0 * 32 + fo8];
                half8 a1 = *(const half8*)&xa1[(fr + 16 * h) * 136 + k0 * 32 + fo8];
#pragma unroll
                for (int j = 0; j < 4; ++j) {
                    acc[j] = MFMA_F16(a0, wf[(j * 4 + k0) * 2], acc[j]);
                    acc[j] = MFMA_F16(a0, wf[(j * 4 + k0) * 2 + 1], acc[j]);
                    acc[j] = MFMA_F16(a1, wf[(j * 4 + k0) * 2], acc[j]);
                }
            }
#pragma unroll
            for (int j = 0; j < 4; ++j) {
                int col = 64 * gg + 16 * j + fr;
                float4 o;
                o.x = acc[j][0] + bias0[j];
                o.y = acc[j][1] + bias0[j];
                o.z = acc[j][2] + bias0[j];
                o.w = acc[j][3] + bias0[j];
                *(float4*)&h1T[col * 36 + qr + 16 * h] = o;
            }
        }
        if (tid >= 384) {
            const int tb = t0 - 128 + s0 * 32 + 32;
#pragma unroll
            for (int q = 0; q < 8; ++q)
                pfx[q] = *(const float4*)&xbase[(size_t)(tb + srow + 4 * q) * 128 + sc4];
        }
    }
    bar_lds();

    // ---- main loop: sc = s0..13 ----
    for (int sc = s0; sc <= 13; ++sc) {
        const int tbase = t0 - 128 + sc * 32;

        // ================= phase B =================
        // LN(sc-2) + store FIRST (stores covered by the scans below)
        if (sc >= 6) {
            const int tbm = tbase - 64;
            const float* s2r = &s2buf[sc & 1][0];
#pragma unroll
            for (int rr = 0; rr < 4; ++rr) {
                int row = 4 * w + rr;
                float2 s2v = *(const float2*)&s2r[row * 132 + lane * 2];
                float y0 = pflnC[rr].x + s2v.x;
                float y1 = pflnC[rr].y + s2v.y;
                float sum = y0 + y1;
                float ss = y0 * y0 + y1 * y1;
#pragma unroll
                for (int off = 32; off > 0; off >>= 1) {
                    sum += __shfl_xor(sum, off, 64);
                    ss  += __shfl_xor(ss, off, 64);
                }
                float mu = sum * (1.0f / 128.0f);
                float var = ss * (1.0f / 128.0f) - mu * mu;
                float inv = rsqrtf(var + 1e-5f);
                float2 o;
                o.x = (y0 - mu) * inv * wv.x + bbv.x;
                o.y = (y1 - mu) * inv * wv.y + bbv.y;
                *(float2*)&obase[(size_t)(tbm + row) * 128 + lane * 2] = o;
            }
        }
        if (isS) {
            if (sc <= 11) {
                // scan1(sc): h1T -> spikes (32 t, vector loads)
                float4 hv[8];
#pragma unroll
                for (int k = 0; k < 8; ++k)
                    hv[k] = *(const float4*)&h1T[tid * 36 + 4 * k];
#pragma unroll
                for (int t = 0; t < 32; ++t) {
                    float hh = (t & 3) == 0 ? hv[t >> 2].x
                             : (t & 3) == 1 ? hv[t >> 2].y
                             : (t & 3) == 2 ? hv[t >> 2].z : hv[t >> 2].w;
                    float h = v1 + (hh - v1) * 0.5f;
                    bool sp = (h >= 1.0f);
                    v1 = sp ? 0.0f : h;
                    spkbuf[t * 264 + tid] = sp ? (unsigned short)0x3C00 : (unsigned short)0;
                }
            }
        } else if (tid < 384) {
            if (sc > s0 && sc <= 12) {
                // scan2(sc-1): h2T -> s2[(sc-1)&1] (32 t, vector loads)
                float* s2w = &s2buf[(sc - 1) & 1][0];
                float4 hv[8];
#pragma unroll
                for (int k = 0; k < 8; ++k)
                    hv[k] = *(const float4*)&h2T[d2 * 36 + 4 * k];
#pragma unroll
                for (int t = 0; t < 32; ++t) {
                    float hh = (t & 3) == 0 ? hv[t >> 2].x
                             : (t & 3) == 1 ? hv[t >> 2].y
                             : (t & 3) == 2 ? hv[t >> 2].z : hv[t >> 2].w;
                    float h = v2 + (hh - v2) * 0.5f;
                    bool sp = (h >= 1.0f);
                    v2 = sp ? 0.0f : h;
                    s2w[t * 132 + d2] = sp ? 1.0f : 0.0f;
                }
            }
        } else {
            if (sc <= 10) {
                // stage x(sc+1) from pfx regs (32 rows)
#pragma unroll
                for (int q = 0; q < 8; ++q) {
                    float4 xv = pfx[q];
                    _Float16 a0 = (_Float16)xv.x, e0 = (_Float16)(xv.x - (float)a0);
                    _Float16 a1 = (_Float16)xv.y, e1 = (_Float16)(xv.y - (float)a1);
                    _Float16 a2 = (_Float16)xv.z, e2 = (_Float16)(xv.z - (float)a2);
                    _Float16 a3 = (_Float16)xv.w, e3 = (_Float16)(xv.w - (float)a3);
                    ushort4 ua = {h2u(a0), h2u(a1), h2u(a2), h2u(a3)};
                    ushort4 ue = {h2u(e0), h2u(e1), h2u(e2), h2u(e3)};
                    *(ushort4*)&xb[0][(srow + 4 * q) * 136 + sc4] = ua;
                    *(ushort4*)&xb[1][(srow + 4 * q) * 136 + sc4] = ue;
                }
            }
        }
        bar_lds();

        // ================= phase A =================
        // prefetch issues FIRST (old by the A-end barrier -> cheap)
        if (sc >= 5 && sc <= 12) {
            // pfln for LN(sc-1), consumed in B(sc+1): rows of x(sc-1)
#pragma unroll
            for (int rr = 0; rr < 4; ++rr)
                pflnN[rr] = *(const float2*)&xbase[(size_t)(tbase - 32 + 4 * w + rr) * 128 + lane * 2];
        }
        if (isS) {
            if (sc <= 11) {
                // GEMM2(sc): spikes @ W2 -> h2T (two 16-row halves)
                const _Float16* sp = (const _Float16*)&spkbuf[0];
                __builtin_amdgcn_s_setprio(1);
#pragma unroll
                for (int h = 0; h < 2; ++h) {
                    f32x4 acc[2];
                    acc[0] = (f32x4){0.f, 0.f, 0.f, 0.f};
                    acc[1] = (f32x4){0.f, 0.f, 0.f, 0.f};
#pragma unroll
                    for (int ks = 0; ks < 8; ++ks) {
                        half8 a = *(const half8*)&sp[(fr + 16 * h) * 264 + ks * 32 + fo8];
#pragma unroll
                        for (int j = 0; j < 2; ++j) {
                            acc[j] = MFMA_F16(a, wf[(j * 8 + ks) * 2], acc[j]);
                            acc[j] = MFMA_F16(a, wf[(j * 8 + ks) * 2 + 1], acc[j]);
                        }
                    }
#pragma unroll
                    for (int j = 0; j < 2; ++j) {
                        int col = 32 * sg + 16 * j + fr;
                        float4 o;
                        o.x = acc[j][0] + bias0[j];
                        o.y = acc[j][1] + bias0[j];
                        o.z = acc[j][2] + bias0[j];
                        o.w = acc[j][3] + bias0[j];
                        *(float4*)&h2T[col * 36 + qr + 16 * h] = o;
                    }
                }
                __builtin_amdgcn_s_setprio(0);
            }
        } else {
            if (tid >= 384 && sc <= 9) {
                // issue pfx x(sc+2) early (consumed in B(sc+1) staging)
#pragma unroll
                for (int q = 0; q < 8; ++q)
                    pfx[q] = *(const float4*)&xbase[(size_t)(tbase + 64 + srow + 4 * q) * 128 + sc4];
            }
            if (sc <= 10) {
                // GEMM1(sc+1): x(sc+1) @ W1 -> h1T (two 16-row halves)
                const _Float16* xa0 = (const _Float16*)&xb[0][0];
                const _Float16* xa1 = (const _Float16*)&xb[1][0];
                __builtin_amdgcn_s_setprio(1);
#pragma unroll
                for (int h = 0; h < 2; ++h) {
                    f32x4 acc[4];
#pragma unroll
                    for (int j = 0; j < 4; ++j) acc[j] = (f32x4){0.f, 0.f, 0.f, 0.f};
#pragma unroll
                    for (int k0 = 0; k0 < 4; ++k0) {
                        half8 a0 = *(const half8*)&xa0[(fr + 16 * h) * 136 + k0 * 32 + fo8];
                        half8 a1 = *(const half8*)&xa1[(fr + 16 * h) * 136 + k0 * 32 + fo8];
#pragma unroll
                        for (int j = 0; j < 4; ++j) {
                            acc[j] = MFMA_F16(a0, wf[(j * 4 + k0) * 2], acc[j]);
                            acc[j] = MFMA_F16(a0, wf[(j * 4 + k0) * 2 + 1], acc[j]);
                            acc[j] = MFMA_F16(a1, wf[(j * 4 + k0) * 2], acc[j]);
                        }
                    }
#pragma unroll
                    for (int j = 0; j < 4; ++j) {
                        int col = 64 * gg + 16 * j + fr;
                        float4 o;
                        o.x = acc[j][0] + bias0[j];
                        o.y = acc[j][1] + bias0[j];
                        o.z = acc[j][2] + bias0[j];
                        o.w = acc[j][3] + bias0[j];
                        *(float4*)&h1T[col * 36 + qr + 16 * h] = o;
                    }
                }
                __builtin_amdgcn_s_setprio(0);
            }
        }
#pragma unroll
        for (int rr = 0; rr < 4; ++rr) pflnC[rr] = pflnN[rr];
        bar_lds();
    }
}

extern "C" void kernel_launch(void* const* d_in, const int* in_sizes, int n_in,
                              void* d_out, int out_size, void* d_ws, size_t ws_size,
                              hipStream_t stream)
{
    const float* x   = (const float*)d_in[0];
    const float* W1  = (const float*)d_in[1];
    const float* b1  = (const float*)d_in[2];
    const float* W2  = (const float*)d_in[3];
    const float* b2  = (const float*)d_in[4];
    const float* lnw = (const float*)d_in[5];
    const float* lnb = (const float*)d_in[6];
    float* out = (float*)d_out;

    dim3 gM(8, 32);   // 256 blocks, 1/CU
    mega_kernel<<<gM, 512, 0, stream>>>(x, W1, W2, b1, b2, lnw, lnb, out);
}